// Round 9
// baseline (316.373 us; speedup 1.0000x reference)
//
#include <hip/hip_runtime.h>
#include <cstdint>
#include <cstddef>

#define C1 128
#define C2 256
#define Hh 56
#define Wd 56
#define HW 3136                  // 56*56
#define NHW 100352               // 32*3136
#define N1 ((size_t)12845056)    // 32*128*3136
#define N2 ((size_t)25690112)    // 32*256*3136
#define XPSZ ((size_t)13778944)  // 32*58*58*128

typedef int v4i __attribute__((ext_vector_type(4)));
typedef int v16i __attribute__((ext_vector_type(16)));

// ---- workspace layout (bytes) ----
static constexpr size_t OFF_XP = 0;
static constexpr size_t OFF_ACC1 = XPSZ;                  // int32, 4*N1
static constexpr size_t OFF_Q1 = OFF_ACC1 + 4 * N1;
static constexpr size_t OFF_Q3 = OFF_Q1 + N1;
static constexpr size_t OFF_WQ1 = OFF_Q3 + N2;
static constexpr size_t OFF_WQ2 = OFF_WQ1 + 147456;
static constexpr size_t OFF_STATS = OFF_WQ2 + 32768;

struct Stats {
  int absmax1, absmax2, pad0, pad1;
  float scale1, e1, s2, e2;
  float scaleq2, e3, sf, ef;
  int sum1[C1]; unsigned sumsq1[C1];
  int min1[C1], max1[C1];
  int sum2[C2]; unsigned sumsq2[C2];
  int min2[C2], max2[C2];
};

// merged: weight prep (both) + stats init. 705 blocks.
__global__ __launch_bounds__(256) void k_prep_all(
    const float* __restrict__ wDW, const float* __restrict__ wPW,
    signed char* __restrict__ wq1t, signed char* __restrict__ wq2t, Stats* st) {
  int b = blockIdx.x, t = threadIdx.x;
  if (b < 576) {
    int idx = b * 256 + t;               // exactly 147456
    int co = idx / 1152, r = idx - co * 1152;
    int ci = r / 9, pos = r - ci * 9;
    int k = pos * 128 + ci;
    wq1t[(size_t)(k >> 4) * 2048 + co * 16 + (k & 15)] = (signed char)(int)wDW[idx];
  } else if (b < 704) {
    int i = (b - 576) * 256 + t;         // exactly 32768
    int co = i >> 7, ci = i & 127;
    wq2t[(size_t)(ci >> 4) * 4096 + co * 16 + (ci & 15)] = (signed char)(int)wPW[i];
  } else {
    if (t == 0) { st->absmax1 = 0; st->absmax2 = 0; }
    for (int c = t; c < C1; c += 256) {
      st->sum1[c] = 0; st->sumsq1[c] = 0; st->min1[c] = 127; st->max1[c] = -128;
    }
    for (int c = t; c < C2; c += 256) {
      st->sum2[c] = 0; st->sumsq2[c] = 0; st->min2[c] = 127; st->max2[c] = -128;
    }
  }
}

// x int32 NCHW -> xp int8 [n][hh(58)][k16(8)][ww(58)][16], borders zeroed.
__global__ __launch_bounds__(256) void k_prep_x2(
    const int* __restrict__ x, signed char* __restrict__ xp) {
  __shared__ signed char lds[56 * 132];
  int t = threadIdx.x;
  int hh = blockIdx.x;             // 0..57
  int n = blockIdx.y;
  int* xpw = (int*)(xp + ((size_t)n * 58 + hh) * 7424);
  if (hh == 0 || hh == 57) {
    for (int o = t; o < 1856; o += 256) xpw[o] = 0;
    return;
  }
  int h = hh - 1;
  const int* xb = x + (size_t)n * C1 * HW + h * 56;
  for (int idx = t; idx < 7168; idx += 256) {
    int c = idx / 56, w = idx - c * 56;
    lds[w * 132 + c] = (signed char)xb[(size_t)c * HW + w];
  }
  __syncthreads();
  for (int o = t; o < 1856; o += 256) {
    int kb = o / 232, r = o - kb * 232, ww = r >> 2, cw = r & 3;
    int val = (ww == 0 || ww == 57) ? 0
              : *(const int*)&lds[(ww - 1) * 132 + kb * 16 + cw * 4];
    xpw[o] = val;
  }
}

__device__ inline v4i ld16_lds(const signed char* p) {
  const int2* q = (const int2*)p;          // 8-byte aligned
  int2 lo = q[0], hi = q[1];
  v4i r; r[0] = lo.x; r[1] = lo.y; r[2] = hi.x; r[3] = hi.y;
  return r;
}

// 3x3 conv 128->128. 784 blocks x 128 pixels x 128 co; wave = 64 pix x 64 co.
// absmax1 + raw acc store in MFMA-register order (256B coalesced).
__global__ __launch_bounds__(256, 4) void k_conv1s(
    const signed char* __restrict__ xp, const signed char* __restrict__ wq1t,
    int* __restrict__ acc1, Stats* st) {
  __shared__ int reda[4];
  int t = threadIdx.x, lane = t & 63, wave = t >> 6;
  int half = lane >> 5, l31 = lane & 31;
  int mw = wave & 1, nw = wave >> 1;
  size_t g0 = (size_t)blockIdx.x * 128;

  const signed char* ab[2];
#pragma unroll
  for (int i = 0; i < 2; ++i) {
    size_t gm = g0 + mw * 64 + i * 32 + l31;
    int n = (int)(gm / HW);
    int p = (int)(gm - (size_t)n * HW);
    int h = p / 56, w = p - h * 56;
    ab[i] = xp + ((size_t)n * 58 + h) * 7424 + w * 16 + half * 928;
  }
  const signed char* bb[2];
#pragma unroll
  for (int j = 0; j < 2; ++j)
    bb[j] = wq1t + (size_t)(nw * 64 + j * 32 + l31) * 16 + half * 2048;

  v16i a1[2][2];
#pragma unroll
  for (int i = 0; i < 2; ++i)
#pragma unroll
    for (int j = 0; j < 2; ++j)
#pragma unroll
      for (int r = 0; r < 16; ++r) a1[i][j][r] = 0;

#pragma unroll
  for (int pos = 0; pos < 9; ++pos) {
    int kh = pos / 3, kw = pos - kh * 3;
    const signed char* a0p = ab[0] + kh * 7424 + kw * 16;
    const signed char* a1p = ab[1] + kh * 7424 + kw * 16;
#pragma unroll
    for (int kb = 0; kb < 8; kb += 2) {
      v4i af0 = *(const v4i*)(a0p + kb * 928);
      v4i af1 = *(const v4i*)(a1p + kb * 928);
      v4i bf0 = *(const v4i*)(bb[0] + pos * 16384 + kb * 2048);
      v4i bf1 = *(const v4i*)(bb[1] + pos * 16384 + kb * 2048);
      a1[0][0] = __builtin_amdgcn_mfma_i32_32x32x32_i8(af0, bf0, a1[0][0], 0, 0, 0);
      a1[0][1] = __builtin_amdgcn_mfma_i32_32x32x32_i8(af0, bf1, a1[0][1], 0, 0, 0);
      a1[1][0] = __builtin_amdgcn_mfma_i32_32x32x32_i8(af1, bf0, a1[1][0], 0, 0, 0);
      a1[1][1] = __builtin_amdgcn_mfma_i32_32x32x32_i8(af1, bf1, a1[1][1], 0, 0, 0);
    }
  }

  int am = 0;
#pragma unroll
  for (int i = 0; i < 2; ++i)
#pragma unroll
    for (int j = 0; j < 2; ++j)
#pragma unroll
      for (int r = 0; r < 16; ++r) am = max(am, abs(a1[i][j][r]));
  for (int off = 32; off; off >>= 1) am = max(am, __shfl_down(am, off, 64));
  if (lane == 0) reda[wave] = am;
  __syncthreads();
  if (t == 0)
    atomicMax(&st->absmax1, max(max(reda[0], reda[1]), max(reda[2], reda[3])));

  int* ob = acc1 + (size_t)blockIdx.x * 16384;
#pragma unroll
  for (int i = 0; i < 2; ++i)
#pragma unroll
    for (int j = 0; j < 2; ++j)
#pragma unroll
      for (int reg = 0; reg < 16; ++reg)
        ob[(((wave * 2 + i) * 2 + j) * 16 + reg) * 64 + lane] = a1[i][j][reg];
}

// read acc1 raw (coalesced), quantize -> q1 [g][128] + per-channel stats.
// scale1 inline from absmax1 (exact integer math). 784 blocks x 128 pix.
__global__ __launch_bounds__(256, 4) void k_qstats1(
    const int* __restrict__ acc1, signed char* __restrict__ q1, Stats* st,
    const float* __restrict__ x_exp, const float* __restrict__ wDW_exp) {
  __shared__ int qti[128 * 34];
  __shared__ int psum[C1], psq[C1], pmn[C1], pmx[C1];
  signed char* qt = (signed char*)qti;
  int t = threadIdx.x, lane = t & 63, wave = t >> 6;
  int half = lane >> 5, l31 = lane & 31;
  int mw = wave & 1, nw = wave >> 1;

  if (t < C1) { psum[t] = 0; psq[t] = 0; pmn[t] = 127; pmx[t] = -128; }
  __syncthreads();

  int v1 = st->absmax1;
  int pw = 31 - __clz(v1 | 1);
  int bw = ((v1 & (v1 - 1)) == 0) ? pw : pw + 1;
  int sh = max(bw - 7, 0);
  float scale1 = exp2f((float)(-sh));
  if (blockIdx.x == 0 && t == 0)
    st->e1 = x_exp[0] + wDW_exp[0] + (float)sh;

  const int* ib = acc1 + (size_t)blockIdx.x * 16384;
#pragma unroll
  for (int j = 0; j < 2; ++j) {
    int sj = 0, sqj = 0, mnj = 127, mxj = -128;
    int c = nw * 64 + j * 32 + l31;
#pragma unroll
    for (int i = 0; i < 2; ++i)
#pragma unroll
      for (int reg = 0; reg < 16; ++reg) {
        int av = ib[(((wave * 2 + i) * 2 + j) * 16 + reg) * 64 + lane];
        int row = (reg & 3) + 8 * (reg >> 2) + 4 * half;
        int pix = mw * 64 + i * 32 + row;
        float r = rintf((float)av * scale1);
        r = fminf(fmaxf(r, -128.f), 127.f);
        int qi = (int)r;
        qt[pix * 136 + c] = (signed char)qi;
        sj += qi; sqj += qi * qi; mnj = min(mnj, qi); mxj = max(mxj, qi);
      }
    sj += __shfl_down(sj, 32, 64);
    sqj += __shfl_down(sqj, 32, 64);
    mnj = min(mnj, __shfl_down(mnj, 32, 64));
    mxj = max(mxj, __shfl_down(mxj, 32, 64));
    if (half == 0) {
      atomicAdd(&psum[c], sj); atomicAdd(&psq[c], sqj);
      atomicMin(&pmn[c], mnj); atomicMax(&pmx[c], mxj);
    }
  }
  __syncthreads();
  if (t < C1) {
    atomicAdd(&st->sum1[t], psum[t]);
    atomicAdd(&st->sumsq1[t], (unsigned)psq[t]);
    atomicMin(&st->min1[t], pmn[t]);
    atomicMax(&st->max1[t], pmx[t]);
  }
  int* q1w = (int*)(q1 + (size_t)blockIdx.x * 128 * 128);
  for (int idx = t; idx < 4096; idx += 256) {
    int pix = idx >> 5, c4 = idx & 31;
    q1w[idx] = qti[pix * 34 + c4];
  }
}

// 1x1 conv 128->256. Block = 128 pix x 256 co; wave = 32 pix.
// bn1 computed in-block from global stats (bit-identical). LDS union:
// stg overlays qti (barrier-separated). STORE=0: absmax2. STORE=1: q3+stats.
template <int STORE>
__global__ __launch_bounds__(256, 4) void k_conv2t(
    const signed char* __restrict__ q1, const signed char* __restrict__ wq2t,
    signed char* __restrict__ q3, Stats* st,
    const float* __restrict__ gamma1, const float* __restrict__ beta1,
    const float* __restrict__ wPW_exp) {
  __shared__ int bufi[8448];               // 33792 B: qti [128][34] / stg [128][264]
  __shared__ int psum[C2], psq[C2], pmn[C2], pmx[C2];
  __shared__ float bnA[C1], bnB[C1], redf[2];
  __shared__ int reda[4];
  signed char* qt = (signed char*)bufi;
  signed char* stg = (signed char*)bufi;

  int t = threadIdx.x, lane = t & 63, wave = t >> 6;
  int half = lane >> 5, l31 = lane & 31;
  size_t g0 = (size_t)blockIdx.x * 128;

  if (STORE) { psum[t] = 0; psq[t] = 0; pmn[t] = 127; pmx[t] = -128; }

  // ---- bn1 (redundant per block; ops identical to old k_bn) ----
  float e1 = st->e1;
  float cand = 0.f;
  if (t < C1) {
    double meanq = (double)st->sum1[t] / (double)NHW;
    double varq = (double)st->sumsq1[t] / (double)NHW - meanq * meanq;
    float se = exp2f(e1);
    float mean = (float)meanq * se;
    float var = (float)varq * se * se;
    float rsq = 1.0f / sqrtf(var + 1e-5f);
    float g = gamma1[t], b = beta1[t];
    float Avv = g * se * rsq;
    float Bvv = b - g * mean * rsq;
    bnA[t] = Avv; bnB[t] = Bvv;
    cand = fmaxf(fabsf(Avv * (float)st->min1[t] + Bvv),
                 fabsf(Avv * (float)st->max1[t] + Bvv));
  }
  if (wave < 2) {
    for (int off = 32; off; off >>= 1) cand = fmaxf(cand, __shfl_down(cand, off, 64));
    if (lane == 0) redf[wave] = cand;
  }
  __syncthreads();
  float rng = fmaxf(redf[0], redf[1]);
  float bwv = ceilf(log2f(rng));
  float s2 = exp2f(7.0f - bwv);
  float e2 = bwv - 7.0f;

  // ---- rebuild q2 tile in LDS ----
  int c4 = t & 31;
  float Av[4], Bv[4];
#pragma unroll
  for (int jj = 0; jj < 4; ++jj) {
    Av[jj] = bnA[c4 * 4 + jj];
    Bv[jj] = bnB[c4 * 4 + jj];
  }
  const int* q1w = (const int*)(q1 + g0 * 128);
#pragma unroll
  for (int k = 0; k < 16; ++k) {
    int idx = k * 256 + t;
    int v = q1w[idx];
    int pix = idx >> 5;
    int outv = 0;
#pragma unroll
    for (int jj = 0; jj < 4; ++jj) {
      int b = (signed char)(v >> (8 * jj));
      float y = Av[jj] * (float)b + Bv[jj];
      float r = rintf(y * s2);
      r = fminf(fmaxf(r, -128.f), 127.f);
      r = fmaxf(r, 0.f);
      outv |= ((int)r & 0xff) << (8 * jj);
    }
    bufi[pix * 34 + c4] = outv;
  }
  __syncthreads();

  // ---- MFMA (ch-loop, acc[4] reused) ----
  int am2 = 0;
  float scale2 = 0.f;
  int sh2 = 0;
  if (STORE) {
    int v2 = st->absmax2;
    int pw = 31 - __clz(v2 | 1);
    int bw = ((v2 & (v2 - 1)) == 0) ? pw : pw + 1;
    sh2 = max(bw - 7, 0);
    scale2 = exp2f((float)(-sh2));
    if (blockIdx.x == 0 && t == 0)
      st->e3 = e2 + wPW_exp[0] + (float)sh2;
  }
  int pq[2][4][4];
#pragma unroll
  for (int ch = 0; ch < 2; ++ch) {
    v16i acc[4];
#pragma unroll
    for (int j = 0; j < 4; ++j)
#pragma unroll
      for (int r = 0; r < 16; ++r) acc[j][r] = 0;
#pragma unroll
    for (int ks = 0; ks < 4; ++ks) {
      v4i af = ld16_lds(&qt[(wave * 32 + l31) * 136 + half * 16 + ks * 32]);
#pragma unroll
      for (int j = 0; j < 4; ++j) {
        v4i bf = *(const v4i*)(wq2t + (size_t)(ks * 2 + half) * 4096 +
                               (ch * 128 + j * 32 + l31) * 16);
        acc[j] = __builtin_amdgcn_mfma_i32_32x32x32_i8(af, bf, acc[j], 0, 0, 0);
      }
    }
    if (STORE == 0) {
#pragma unroll
      for (int j = 0; j < 4; ++j)
#pragma unroll
        for (int r = 0; r < 16; ++r) am2 = max(am2, abs(acc[j][r]));
    } else {
#pragma unroll
      for (int j = 0; j < 4; ++j) {
        int c = ch * 128 + j * 32 + l31;
        int sj = 0, sqj = 0, mnj = 127, mxj = -128;
        int pk[4] = {0, 0, 0, 0};
#pragma unroll
        for (int reg = 0; reg < 16; ++reg) {
          float r = rintf((float)acc[j][reg] * scale2);
          r = fminf(fmaxf(r, -128.f), 127.f);
          int qi = (int)r;
          pk[reg >> 2] |= (qi & 0xff) << ((reg & 3) * 8);
          sj += qi; sqj += qi * qi; mnj = min(mnj, qi); mxj = max(mxj, qi);
        }
#pragma unroll
        for (int k = 0; k < 4; ++k) pq[ch][j][k] = pk[k];
        sj += __shfl_down(sj, 32, 64);
        sqj += __shfl_down(sqj, 32, 64);
        mnj = min(mnj, __shfl_down(mnj, 32, 64));
        mxj = max(mxj, __shfl_down(mxj, 32, 64));
        if (half == 0) {
          atomicAdd(&psum[c], sj); atomicAdd(&psq[c], sqj);
          atomicMin(&pmn[c], mnj); atomicMax(&pmx[c], mxj);
        }
      }
    }
  }

  if (STORE == 0) {
    for (int off = 32; off; off >>= 1) am2 = max(am2, __shfl_down(am2, off, 64));
    if (lane == 0) reda[wave] = am2;
    __syncthreads();
    if (t == 0)
      atomicMax(&st->absmax2, max(max(reda[0], reda[1]), max(reda[2], reda[3])));
  } else {
    __syncthreads();   // all qt reads done; safe to overlay stg
#pragma unroll
    for (int ch = 0; ch < 2; ++ch)
#pragma unroll
      for (int j = 0; j < 4; ++j)
#pragma unroll
        for (int k = 0; k < 4; ++k) {
          int word = pq[ch][j][k];
#pragma unroll
          for (int b = 0; b < 4; ++b) {
            int row = b + 8 * k + 4 * half;
            stg[(wave * 32 + row) * 264 + ch * 128 + j * 32 + l31] =
                (signed char)(word >> (8 * b));
          }
        }
    __syncthreads();
    atomicAdd(&st->sum2[t], psum[t]);
    atomicAdd(&st->sumsq2[t], (unsigned)psq[t]);
    atomicMin(&st->min2[t], pmn[t]);
    atomicMax(&st->max2[t], pmx[t]);
    int* q3w = (int*)(q3 + g0 * 256);
#pragma unroll
    for (int k = 0; k < 32; ++k) {
      int idx = k * 256 + t;
      int pix = idx >> 6, cw = idx & 63;
      q3w[idx] = *(const int*)&stg[pix * 264 + cw * 4];
    }
  }
}

// final: bn2 in-block (bit-identical), then q3 [g][256] -> out NCHW float
// via LDS transpose; all global access coalesced.
__global__ __launch_bounds__(256) void k_out(
    const signed char* __restrict__ q3, const Stats* __restrict__ st,
    const float* __restrict__ gamma2, const float* __restrict__ beta2,
    float* __restrict__ out) {
  __shared__ signed char lds[64 * 260];
  __shared__ float bnA2[C2], bnB2[C2], redf2[4];
  int t = threadIdx.x, lane = t & 63, wave = t >> 6;
  size_t g0 = (size_t)blockIdx.x * 64;     // 1568 blocks
  int n = (int)(g0 / HW), p0 = (int)(g0 - (size_t)n * HW);
  const int* q3w = (const int*)(q3 + g0 * 256);
#pragma unroll
  for (int k = 0; k < 16; ++k) {
    int idx = k * 256 + t;
    int pix = idx >> 6, cw = idx & 63;
    *(int*)&lds[pix * 260 + cw * 4] = q3w[idx];
  }
  // bn2 (redundant per block; ops identical to old k_bn)
  float e3 = st->e3;
  {
    double meanq = (double)st->sum2[t] / (double)NHW;
    double varq = (double)st->sumsq2[t] / (double)NHW - meanq * meanq;
    float se = exp2f(e3);
    float mean = (float)meanq * se;
    float var = (float)varq * se * se;
    float rsq = 1.0f / sqrtf(var + 1e-5f);
    float g = gamma2[t], b = beta2[t];
    float Avv = g * se * rsq;
    float Bvv = b - g * mean * rsq;
    bnA2[t] = Avv; bnB2[t] = Bvv;
    float cand = fmaxf(fabsf(Avv * (float)st->min2[t] + Bvv),
                       fabsf(Avv * (float)st->max2[t] + Bvv));
    for (int off = 32; off; off >>= 1) cand = fmaxf(cand, __shfl_down(cand, off, 64));
    if (lane == 0) redf2[wave] = cand;
  }
  __syncthreads();
  float rng = fmaxf(fmaxf(redf2[0], redf2[1]), fmaxf(redf2[2], redf2[3]));
  float bwv = ceilf(log2f(rng));
  float sf = exp2f(7.0f - bwv);
  if (blockIdx.x == 0 && t == 0) out[N2] = bwv - 7.0f;

  float* ob = out + (size_t)n * C2 * HW + p0 + lane;
#pragma unroll
  for (int cg = 0; cg < 16; ++cg) {
    int v = *(const int*)&lds[lane * 260 + wave * 64 + cg * 4];
#pragma unroll
    for (int jj = 0; jj < 4; ++jj) {
      int c = wave * 64 + cg * 4 + jj;
      float y = bnA2[c] * (float)((signed char)(v >> (8 * jj))) + bnB2[c];
      float r = rintf(y * sf);
      r = fminf(fmaxf(r, -128.f), 127.f);
      ob[(size_t)c * HW] = fmaxf(r, 0.f);
    }
  }
}

extern "C" void kernel_launch(void* const* d_in, const int* in_sizes, int n_in,
                              void* d_out, int out_size, void* d_ws, size_t ws_size,
                              hipStream_t stream) {
  const int* x = (const int*)d_in[0];
  const float* x_exp = (const float*)d_in[1];
  const float* wDW = (const float*)d_in[2];
  const float* wDW_exp = (const float*)d_in[3];
  const float* wPW = (const float*)d_in[4];
  const float* wPW_exp = (const float*)d_in[5];
  const float* gamma1 = (const float*)d_in[6];
  const float* beta1 = (const float*)d_in[7];
  const float* gamma2 = (const float*)d_in[8];
  const float* beta2 = (const float*)d_in[9];
  float* out = (float*)d_out;

  char* ws = (char*)d_ws;
  signed char* xp2 = (signed char*)(ws + OFF_XP);
  int* acc1 = (int*)(ws + OFF_ACC1);
  signed char* q1 = (signed char*)(ws + OFF_Q1);
  signed char* q3 = (signed char*)(ws + OFF_Q3);
  signed char* wq1t = (signed char*)(ws + OFF_WQ1);
  signed char* wq2t = (signed char*)(ws + OFF_WQ2);
  Stats* st = (Stats*)(ws + OFF_STATS);

  hipLaunchKernelGGL(k_prep_all, dim3(705), dim3(256), 0, stream,
                     wDW, wPW, wq1t, wq2t, st);
  hipLaunchKernelGGL(k_prep_x2, dim3(58, 32), dim3(256), 0, stream, x, xp2);

  hipLaunchKernelGGL(k_conv1s, dim3(784), dim3(256), 0, stream,
                     xp2, wq1t, acc1, st);
  hipLaunchKernelGGL(k_qstats1, dim3(784), dim3(256), 0, stream,
                     acc1, q1, st, x_exp, wDW_exp);

  hipLaunchKernelGGL(k_conv2t<0>, dim3(784), dim3(256), 0, stream,
                     q1, wq2t, q3, st, gamma1, beta1, wPW_exp);
  hipLaunchKernelGGL(k_conv2t<1>, dim3(784), dim3(256), 0, stream,
                     q1, wq2t, q3, st, gamma1, beta1, wPW_exp);

  hipLaunchKernelGGL(k_out, dim3(1568), dim3(256), 0, stream,
                     q3, st, gamma2, beta2, out);
}

// Round 10
// 304.012 us; speedup vs baseline: 1.0407x; 1.0407x over previous
//
#include <hip/hip_runtime.h>
#include <cstdint>
#include <cstddef>

#define C1 128
#define C2 256
#define Hh 56
#define Wd 56
#define HW 3136                  // 56*56
#define NHW 100352               // 32*3136
#define N1 ((size_t)12845056)    // 32*128*3136
#define N2 ((size_t)25690112)    // 32*256*3136
#define XPSZ ((size_t)13778944)  // 32*58*58*128

typedef int v4i __attribute__((ext_vector_type(4)));
typedef int v16i __attribute__((ext_vector_type(16)));

// ---- workspace layout (bytes) ----
static constexpr size_t OFF_XP = 0;
static constexpr size_t OFF_ACC1 = XPSZ;                  // int32, 4*N1
static constexpr size_t OFF_Q1 = OFF_ACC1 + 4 * N1;
static constexpr size_t OFF_Q3 = OFF_Q1 + N1;
static constexpr size_t OFF_WQ1 = OFF_Q3 + N2;
static constexpr size_t OFF_WQ2 = OFF_WQ1 + 147456;
static constexpr size_t OFF_STATS = OFF_WQ2 + 32768;

struct Stats {
  int absmax1, absmax2, pad0, pad1;
  float scale1, e1, s2, e2;
  float scaleq2, e3, sf, ef;
  int sum1[C1]; unsigned sumsq1[C1];
  int min1[C1], max1[C1];
  int sum2[C2]; unsigned sumsq2[C2];
  int min2[C2], max2[C2];
};

// merged: weight prep (both) + stats init. 705 blocks.
__global__ __launch_bounds__(256) void k_prep_all(
    const float* __restrict__ wDW, const float* __restrict__ wPW,
    signed char* __restrict__ wq1t, signed char* __restrict__ wq2t, Stats* st) {
  int b = blockIdx.x, t = threadIdx.x;
  if (b < 576) {
    int idx = b * 256 + t;               // exactly 147456
    int co = idx / 1152, r = idx - co * 1152;
    int ci = r / 9, pos = r - ci * 9;
    int k = pos * 128 + ci;
    wq1t[(size_t)(k >> 4) * 2048 + co * 16 + (k & 15)] = (signed char)(int)wDW[idx];
  } else if (b < 704) {
    int i = (b - 576) * 256 + t;         // exactly 32768
    int co = i >> 7, ci = i & 127;
    wq2t[(size_t)(ci >> 4) * 4096 + co * 16 + (ci & 15)] = (signed char)(int)wPW[i];
  } else {
    if (t == 0) { st->absmax1 = 0; st->absmax2 = 0; }
    for (int c = t; c < C1; c += 256) {
      st->sum1[c] = 0; st->sumsq1[c] = 0; st->min1[c] = 127; st->max1[c] = -128;
    }
    for (int c = t; c < C2; c += 256) {
      st->sum2[c] = 0; st->sumsq2[c] = 0; st->min2[c] = 127; st->max2[c] = -128;
    }
  }
}

// x int32 NCHW -> xp int8 [n][hh(58)][k16(8)][ww(58)][16], borders zeroed.
__global__ __launch_bounds__(256) void k_prep_x2(
    const int* __restrict__ x, signed char* __restrict__ xp) {
  __shared__ signed char lds[56 * 132];
  int t = threadIdx.x;
  int hh = blockIdx.x;             // 0..57
  int n = blockIdx.y;
  int* xpw = (int*)(xp + ((size_t)n * 58 + hh) * 7424);
  if (hh == 0 || hh == 57) {
    for (int o = t; o < 1856; o += 256) xpw[o] = 0;
    return;
  }
  int h = hh - 1;
  const int* xb = x + (size_t)n * C1 * HW + h * 56;
  for (int idx = t; idx < 7168; idx += 256) {
    int c = idx / 56, w = idx - c * 56;
    lds[w * 132 + c] = (signed char)xb[(size_t)c * HW + w];
  }
  __syncthreads();
  for (int o = t; o < 1856; o += 256) {
    int kb = o / 232, r = o - kb * 232, ww = r >> 2, cw = r & 3;
    int val = (ww == 0 || ww == 57) ? 0
              : *(const int*)&lds[(ww - 1) * 132 + kb * 16 + cw * 4];
    xpw[o] = val;
  }
}

__device__ inline v4i ld16_lds(const signed char* p) {
  const int2* q = (const int2*)p;          // 8-byte aligned
  int2 lo = q[0], hi = q[1];
  v4i r; r[0] = lo.x; r[1] = lo.y; r[2] = hi.x; r[3] = hi.y;
  return r;
}

// 3x3 conv 128->128. 784 blocks x 128 pixels x 128 co; wave = 64 pix x 64 co.
// absmax1 + raw acc store in MFMA-register order (256B coalesced).
__global__ __launch_bounds__(256, 4) void k_conv1s(
    const signed char* __restrict__ xp, const signed char* __restrict__ wq1t,
    int* __restrict__ acc1, Stats* st) {
  __shared__ int reda[4];
  int t = threadIdx.x, lane = t & 63, wave = t >> 6;
  int half = lane >> 5, l31 = lane & 31;
  int mw = wave & 1, nw = wave >> 1;
  size_t g0 = (size_t)blockIdx.x * 128;

  const signed char* ab[2];
#pragma unroll
  for (int i = 0; i < 2; ++i) {
    size_t gm = g0 + mw * 64 + i * 32 + l31;
    int n = (int)(gm / HW);
    int p = (int)(gm - (size_t)n * HW);
    int h = p / 56, w = p - h * 56;
    ab[i] = xp + ((size_t)n * 58 + h) * 7424 + w * 16 + half * 928;
  }
  const signed char* bb[2];
#pragma unroll
  for (int j = 0; j < 2; ++j)
    bb[j] = wq1t + (size_t)(nw * 64 + j * 32 + l31) * 16 + half * 2048;

  v16i a1[2][2];
#pragma unroll
  for (int i = 0; i < 2; ++i)
#pragma unroll
    for (int j = 0; j < 2; ++j)
#pragma unroll
      for (int r = 0; r < 16; ++r) a1[i][j][r] = 0;

#pragma unroll
  for (int pos = 0; pos < 9; ++pos) {
    int kh = pos / 3, kw = pos - kh * 3;
    const signed char* a0p = ab[0] + kh * 7424 + kw * 16;
    const signed char* a1p = ab[1] + kh * 7424 + kw * 16;
#pragma unroll
    for (int kb = 0; kb < 8; kb += 2) {
      v4i af0 = *(const v4i*)(a0p + kb * 928);
      v4i af1 = *(const v4i*)(a1p + kb * 928);
      v4i bf0 = *(const v4i*)(bb[0] + pos * 16384 + kb * 2048);
      v4i bf1 = *(const v4i*)(bb[1] + pos * 16384 + kb * 2048);
      a1[0][0] = __builtin_amdgcn_mfma_i32_32x32x32_i8(af0, bf0, a1[0][0], 0, 0, 0);
      a1[0][1] = __builtin_amdgcn_mfma_i32_32x32x32_i8(af0, bf1, a1[0][1], 0, 0, 0);
      a1[1][0] = __builtin_amdgcn_mfma_i32_32x32x32_i8(af1, bf0, a1[1][0], 0, 0, 0);
      a1[1][1] = __builtin_amdgcn_mfma_i32_32x32x32_i8(af1, bf1, a1[1][1], 0, 0, 0);
    }
  }

  int am = 0;
#pragma unroll
  for (int i = 0; i < 2; ++i)
#pragma unroll
    for (int j = 0; j < 2; ++j)
#pragma unroll
      for (int r = 0; r < 16; ++r) am = max(am, abs(a1[i][j][r]));
  for (int off = 32; off; off >>= 1) am = max(am, __shfl_down(am, off, 64));
  if (lane == 0) reda[wave] = am;
  __syncthreads();
  if (t == 0)
    atomicMax(&st->absmax1, max(max(reda[0], reda[1]), max(reda[2], reda[3])));

  int* ob = acc1 + (size_t)blockIdx.x * 16384;
#pragma unroll
  for (int i = 0; i < 2; ++i)
#pragma unroll
    for (int j = 0; j < 2; ++j)
#pragma unroll
      for (int reg = 0; reg < 16; ++reg)
        ob[(((wave * 2 + i) * 2 + j) * 16 + reg) * 64 + lane] = a1[i][j][reg];
}

// read acc1 raw (coalesced), quantize -> q1 [g][128] + per-channel stats.
// scale1 inline from absmax1 (exact integer math). 784 blocks x 128 pix.
__global__ __launch_bounds__(256, 4) void k_qstats1(
    const int* __restrict__ acc1, signed char* __restrict__ q1, Stats* st,
    const float* __restrict__ x_exp, const float* __restrict__ wDW_exp) {
  __shared__ int qti[128 * 34];
  __shared__ int psum[C1], psq[C1], pmn[C1], pmx[C1];
  signed char* qt = (signed char*)qti;
  int t = threadIdx.x, lane = t & 63, wave = t >> 6;
  int half = lane >> 5, l31 = lane & 31;
  int mw = wave & 1, nw = wave >> 1;

  if (t < C1) { psum[t] = 0; psq[t] = 0; pmn[t] = 127; pmx[t] = -128; }
  __syncthreads();

  int v1 = st->absmax1;
  int pw = 31 - __clz(v1 | 1);
  int bw = ((v1 & (v1 - 1)) == 0) ? pw : pw + 1;
  int sh = max(bw - 7, 0);
  float scale1 = exp2f((float)(-sh));
  if (blockIdx.x == 0 && t == 0)
    st->e1 = x_exp[0] + wDW_exp[0] + (float)sh;

  const int* ib = acc1 + (size_t)blockIdx.x * 16384;
#pragma unroll
  for (int j = 0; j < 2; ++j) {
    int sj = 0, sqj = 0, mnj = 127, mxj = -128;
    int c = nw * 64 + j * 32 + l31;
#pragma unroll
    for (int i = 0; i < 2; ++i)
#pragma unroll
      for (int reg = 0; reg < 16; ++reg) {
        int av = ib[(((wave * 2 + i) * 2 + j) * 16 + reg) * 64 + lane];
        int row = (reg & 3) + 8 * (reg >> 2) + 4 * half;
        int pix = mw * 64 + i * 32 + row;
        float r = rintf((float)av * scale1);
        r = fminf(fmaxf(r, -128.f), 127.f);
        int qi = (int)r;
        qt[pix * 136 + c] = (signed char)qi;
        sj += qi; sqj += qi * qi; mnj = min(mnj, qi); mxj = max(mxj, qi);
      }
    sj += __shfl_down(sj, 32, 64);
    sqj += __shfl_down(sqj, 32, 64);
    mnj = min(mnj, __shfl_down(mnj, 32, 64));
    mxj = max(mxj, __shfl_down(mxj, 32, 64));
    if (half == 0) {
      atomicAdd(&psum[c], sj); atomicAdd(&psq[c], sqj);
      atomicMin(&pmn[c], mnj); atomicMax(&pmx[c], mxj);
    }
  }
  __syncthreads();
  if (t < C1) {
    atomicAdd(&st->sum1[t], psum[t]);
    atomicAdd(&st->sumsq1[t], (unsigned)psq[t]);
    atomicMin(&st->min1[t], pmn[t]);
    atomicMax(&st->max1[t], pmx[t]);
  }
  int* q1w = (int*)(q1 + (size_t)blockIdx.x * 128 * 128);
  for (int idx = t; idx < 4096; idx += 256) {
    int pix = idx >> 5, c4 = idx & 31;
    q1w[idx] = qti[pix * 34 + c4];
  }
}

// 1x1 conv 128->256. Block = 128 pix x 256 co; wave = 32 pix.
// bn1 computed in-block from global stats (bit-identical). LDS union:
// stg overlays qti (barrier-separated). STORE=0: absmax2. STORE=1: q3+stats.
// launch_bounds (256,2): ~116 live VGPRs — (256,4) caused scratch spills (r9).
template <int STORE>
__global__ __launch_bounds__(256, 2) void k_conv2t(
    const signed char* __restrict__ q1, const signed char* __restrict__ wq2t,
    signed char* __restrict__ q3, Stats* st,
    const float* __restrict__ gamma1, const float* __restrict__ beta1,
    const float* __restrict__ wPW_exp) {
  __shared__ int bufi[8448];               // 33792 B: qti [128][34] / stg [128][264]
  __shared__ int psum[C2], psq[C2], pmn[C2], pmx[C2];
  __shared__ float bnA[C1], bnB[C1], redf[2];
  __shared__ int reda[4];
  signed char* qt = (signed char*)bufi;
  signed char* stg = (signed char*)bufi;

  int t = threadIdx.x, lane = t & 63, wave = t >> 6;
  int half = lane >> 5, l31 = lane & 31;
  size_t g0 = (size_t)blockIdx.x * 128;

  if (STORE) { psum[t] = 0; psq[t] = 0; pmn[t] = 127; pmx[t] = -128; }

  // ---- bn1 (redundant per block; ops identical to reference chain) ----
  float e1 = st->e1;
  float cand = 0.f;
  if (t < C1) {
    double meanq = (double)st->sum1[t] / (double)NHW;
    double varq = (double)st->sumsq1[t] / (double)NHW - meanq * meanq;
    float se = exp2f(e1);
    float mean = (float)meanq * se;
    float var = (float)varq * se * se;
    float rsq = 1.0f / sqrtf(var + 1e-5f);
    float g = gamma1[t], b = beta1[t];
    float Avv = g * se * rsq;
    float Bvv = b - g * mean * rsq;
    bnA[t] = Avv; bnB[t] = Bvv;
    cand = fmaxf(fabsf(Avv * (float)st->min1[t] + Bvv),
                 fabsf(Avv * (float)st->max1[t] + Bvv));
  }
  if (wave < 2) {
    for (int off = 32; off; off >>= 1) cand = fmaxf(cand, __shfl_down(cand, off, 64));
    if (lane == 0) redf[wave] = cand;
  }
  __syncthreads();
  float rng = fmaxf(redf[0], redf[1]);
  float bwv = ceilf(log2f(rng));
  float s2 = exp2f(7.0f - bwv);
  float e2 = bwv - 7.0f;

  // ---- rebuild q2 tile in LDS ----
  int c4 = t & 31;
  float Av[4], Bv[4];
#pragma unroll
  for (int jj = 0; jj < 4; ++jj) {
    Av[jj] = bnA[c4 * 4 + jj];
    Bv[jj] = bnB[c4 * 4 + jj];
  }
  const int* q1w = (const int*)(q1 + g0 * 128);
#pragma unroll
  for (int k = 0; k < 16; ++k) {
    int idx = k * 256 + t;
    int v = q1w[idx];
    int pix = idx >> 5;
    int outv = 0;
#pragma unroll
    for (int jj = 0; jj < 4; ++jj) {
      int b = (signed char)(v >> (8 * jj));
      float y = Av[jj] * (float)b + Bv[jj];
      float r = rintf(y * s2);
      r = fminf(fmaxf(r, -128.f), 127.f);
      r = fmaxf(r, 0.f);
      outv |= ((int)r & 0xff) << (8 * jj);
    }
    bufi[pix * 34 + c4] = outv;
  }
  __syncthreads();

  // ---- MFMA (ch-loop, acc[4] reused) ----
  int am2 = 0;
  float scale2 = 0.f;
  int sh2 = 0;
  if (STORE) {
    int v2 = st->absmax2;
    int pw = 31 - __clz(v2 | 1);
    int bw = ((v2 & (v2 - 1)) == 0) ? pw : pw + 1;
    sh2 = max(bw - 7, 0);
    scale2 = exp2f((float)(-sh2));
    if (blockIdx.x == 0 && t == 0)
      st->e3 = e2 + wPW_exp[0] + (float)sh2;
  }
  int pq[2][4][4];
#pragma unroll
  for (int ch = 0; ch < 2; ++ch) {
    v16i acc[4];
#pragma unroll
    for (int j = 0; j < 4; ++j)
#pragma unroll
      for (int r = 0; r < 16; ++r) acc[j][r] = 0;
#pragma unroll
    for (int ks = 0; ks < 4; ++ks) {
      v4i af = ld16_lds(&qt[(wave * 32 + l31) * 136 + half * 16 + ks * 32]);
#pragma unroll
      for (int j = 0; j < 4; ++j) {
        v4i bf = *(const v4i*)(wq2t + (size_t)(ks * 2 + half) * 4096 +
                               (ch * 128 + j * 32 + l31) * 16);
        acc[j] = __builtin_amdgcn_mfma_i32_32x32x32_i8(af, bf, acc[j], 0, 0, 0);
      }
    }
    if (STORE == 0) {
#pragma unroll
      for (int j = 0; j < 4; ++j)
#pragma unroll
        for (int r = 0; r < 16; ++r) am2 = max(am2, abs(acc[j][r]));
    } else {
#pragma unroll
      for (int j = 0; j < 4; ++j) {
        int c = ch * 128 + j * 32 + l31;
        int sj = 0, sqj = 0, mnj = 127, mxj = -128;
        int pk[4] = {0, 0, 0, 0};
#pragma unroll
        for (int reg = 0; reg < 16; ++reg) {
          float r = rintf((float)acc[j][reg] * scale2);
          r = fminf(fmaxf(r, -128.f), 127.f);
          int qi = (int)r;
          pk[reg >> 2] |= (qi & 0xff) << ((reg & 3) * 8);
          sj += qi; sqj += qi * qi; mnj = min(mnj, qi); mxj = max(mxj, qi);
        }
#pragma unroll
        for (int k = 0; k < 4; ++k) pq[ch][j][k] = pk[k];
        sj += __shfl_down(sj, 32, 64);
        sqj += __shfl_down(sqj, 32, 64);
        mnj = min(mnj, __shfl_down(mnj, 32, 64));
        mxj = max(mxj, __shfl_down(mxj, 32, 64));
        if (half == 0) {
          atomicAdd(&psum[c], sj); atomicAdd(&psq[c], sqj);
          atomicMin(&pmn[c], mnj); atomicMax(&pmx[c], mxj);
        }
      }
    }
  }

  if (STORE == 0) {
    for (int off = 32; off; off >>= 1) am2 = max(am2, __shfl_down(am2, off, 64));
    if (lane == 0) reda[wave] = am2;
    __syncthreads();
    if (t == 0)
      atomicMax(&st->absmax2, max(max(reda[0], reda[1]), max(reda[2], reda[3])));
  } else {
    __syncthreads();   // all qt reads done; safe to overlay stg
#pragma unroll
    for (int ch = 0; ch < 2; ++ch)
#pragma unroll
      for (int j = 0; j < 4; ++j)
#pragma unroll
        for (int k = 0; k < 4; ++k) {
          int word = pq[ch][j][k];
#pragma unroll
          for (int b = 0; b < 4; ++b) {
            int row = b + 8 * k + 4 * half;
            stg[(wave * 32 + row) * 264 + ch * 128 + j * 32 + l31] =
                (signed char)(word >> (8 * b));
          }
        }
    __syncthreads();
    atomicAdd(&st->sum2[t], psum[t]);
    atomicAdd(&st->sumsq2[t], (unsigned)psq[t]);
    atomicMin(&st->min2[t], pmn[t]);
    atomicMax(&st->max2[t], pmx[t]);
    int* q3w = (int*)(q3 + g0 * 256);
#pragma unroll
    for (int k = 0; k < 32; ++k) {
      int idx = k * 256 + t;
      int pix = idx >> 6, cw = idx & 63;
      q3w[idx] = *(const int*)&stg[pix * 264 + cw * 4];
    }
  }
}

// final: bn2 in-block (bit-identical), then q3 [g][256] -> out NCHW float
// via LDS transpose; all global access coalesced.
__global__ __launch_bounds__(256) void k_out(
    const signed char* __restrict__ q3, const Stats* __restrict__ st,
    const float* __restrict__ gamma2, const float* __restrict__ beta2,
    float* __restrict__ out) {
  __shared__ signed char lds[64 * 260];
  __shared__ float bnA2[C2], bnB2[C2], redf2[4];
  int t = threadIdx.x, lane = t & 63, wave = t >> 6;
  size_t g0 = (size_t)blockIdx.x * 64;     // 1568 blocks
  int n = (int)(g0 / HW), p0 = (int)(g0 - (size_t)n * HW);
  const int* q3w = (const int*)(q3 + g0 * 256);
#pragma unroll
  for (int k = 0; k < 16; ++k) {
    int idx = k * 256 + t;
    int pix = idx >> 6, cw = idx & 63;
    *(int*)&lds[pix * 260 + cw * 4] = q3w[idx];
  }
  // bn2 (redundant per block; ops identical to reference chain)
  float e3 = st->e3;
  {
    double meanq = (double)st->sum2[t] / (double)NHW;
    double varq = (double)st->sumsq2[t] / (double)NHW - meanq * meanq;
    float se = exp2f(e3);
    float mean = (float)meanq * se;
    float var = (float)varq * se * se;
    float rsq = 1.0f / sqrtf(var + 1e-5f);
    float g = gamma2[t], b = beta2[t];
    float Avv = g * se * rsq;
    float Bvv = b - g * mean * rsq;
    bnA2[t] = Avv; bnB2[t] = Bvv;
    float cand = fmaxf(fabsf(Avv * (float)st->min2[t] + Bvv),
                       fabsf(Avv * (float)st->max2[t] + Bvv));
    for (int off = 32; off; off >>= 1) cand = fmaxf(cand, __shfl_down(cand, off, 64));
    if (lane == 0) redf2[wave] = cand;
  }
  __syncthreads();
  float rng = fmaxf(fmaxf(redf2[0], redf2[1]), fmaxf(redf2[2], redf2[3]));
  float bwv = ceilf(log2f(rng));
  float sf = exp2f(7.0f - bwv);
  if (blockIdx.x == 0 && t == 0) out[N2] = bwv - 7.0f;

  float* ob = out + (size_t)n * C2 * HW + p0 + lane;
#pragma unroll
  for (int cg = 0; cg < 16; ++cg) {
    int v = *(const int*)&lds[lane * 260 + wave * 64 + cg * 4];
#pragma unroll
    for (int jj = 0; jj < 4; ++jj) {
      int c = wave * 64 + cg * 4 + jj;
      float y = bnA2[c] * (float)((signed char)(v >> (8 * jj))) + bnB2[c];
      float r = rintf(y * sf);
      r = fminf(fmaxf(r, -128.f), 127.f);
      ob[(size_t)c * HW] = fmaxf(r, 0.f);
    }
  }
}

extern "C" void kernel_launch(void* const* d_in, const int* in_sizes, int n_in,
                              void* d_out, int out_size, void* d_ws, size_t ws_size,
                              hipStream_t stream) {
  const int* x = (const int*)d_in[0];
  const float* x_exp = (const float*)d_in[1];
  const float* wDW = (const float*)d_in[2];
  const float* wDW_exp = (const float*)d_in[3];
  const float* wPW = (const float*)d_in[4];
  const float* wPW_exp = (const float*)d_in[5];
  const float* gamma1 = (const float*)d_in[6];
  const float* beta1 = (const float*)d_in[7];
  const float* gamma2 = (const float*)d_in[8];
  const float* beta2 = (const float*)d_in[9];
  float* out = (float*)d_out;

  char* ws = (char*)d_ws;
  signed char* xp2 = (signed char*)(ws + OFF_XP);
  int* acc1 = (int*)(ws + OFF_ACC1);
  signed char* q1 = (signed char*)(ws + OFF_Q1);
  signed char* q3 = (signed char*)(ws + OFF_Q3);
  signed char* wq1t = (signed char*)(ws + OFF_WQ1);
  signed char* wq2t = (signed char*)(ws + OFF_WQ2);
  Stats* st = (Stats*)(ws + OFF_STATS);

  hipLaunchKernelGGL(k_prep_all, dim3(705), dim3(256), 0, stream,
                     wDW, wPW, wq1t, wq2t, st);
  hipLaunchKernelGGL(k_prep_x2, dim3(58, 32), dim3(256), 0, stream, x, xp2);

  hipLaunchKernelGGL(k_conv1s, dim3(784), dim3(256), 0, stream,
                     xp2, wq1t, acc1, st);
  hipLaunchKernelGGL(k_qstats1, dim3(784), dim3(256), 0, stream,
                     acc1, q1, st, x_exp, wDW_exp);

  hipLaunchKernelGGL(k_conv2t<0>, dim3(784), dim3(256), 0, stream,
                     q1, wq2t, q3, st, gamma1, beta1, wPW_exp);
  hipLaunchKernelGGL(k_conv2t<1>, dim3(784), dim3(256), 0, stream,
                     q1, wq2t, q3, st, gamma1, beta1, wPW_exp);

  hipLaunchKernelGGL(k_out, dim3(1568), dim3(256), 0, stream,
                     q3, st, gamma2, beta2, out);
}

// Round 11
// 301.722 us; speedup vs baseline: 1.0486x; 1.0076x over previous
//
#include <hip/hip_runtime.h>
#include <cstdint>
#include <cstddef>

#define C1 128
#define C2 256
#define Hh 56
#define Wd 56
#define HW 3136                  // 56*56
#define NHW 100352               // 32*3136
#define N1 ((size_t)12845056)    // 32*128*3136
#define N2 ((size_t)25690112)    // 32*256*3136
#define XPSZ ((size_t)13778944)  // 32*58*58*128

typedef int v4i __attribute__((ext_vector_type(4)));
typedef int v16i __attribute__((ext_vector_type(16)));

// ---- workspace layout (bytes) ----
static constexpr size_t OFF_XP = 0;
static constexpr size_t OFF_ACC1 = XPSZ;                  // int32, 4*N1
static constexpr size_t OFF_Q1 = OFF_ACC1 + 4 * N1;
static constexpr size_t OFF_Q3 = OFF_Q1 + N1;
static constexpr size_t OFF_WQ1 = OFF_Q3 + N2;
static constexpr size_t OFF_WQ2 = OFF_WQ1 + 147456;
static constexpr size_t OFF_STATS = OFF_WQ2 + 32768;

struct Stats {
  int absmax1, absmax2, pad0, pad1;
  float scale1, e1, s2, e2;
  float scaleq2, e3, sf, ef;
  int sum1[C1]; unsigned sumsq1[C1];
  int min1[C1], max1[C1];
  int sum2[C2]; unsigned sumsq2[C2];
  int min2[C2], max2[C2];
};

// merged prep: [0,58*32) = x transpose rows; then weight prep; last = stats init.
// x int32 NCHW -> xp int8 [n][hh(58)][k16(8)][ww(58)][16], borders zeroed.
__global__ __launch_bounds__(256) void k_prep(
    const int* __restrict__ x, const float* __restrict__ wDW,
    const float* __restrict__ wPW, signed char* __restrict__ xp,
    signed char* __restrict__ wq1t, signed char* __restrict__ wq2t, Stats* st) {
  __shared__ signed char lds[56 * 132];
  int b = blockIdx.x, t = threadIdx.x;
  if (b < 1856) {                        // 58 * 32
    int hh = b % 58, n = b / 58;
    int* xpw = (int*)(xp + ((size_t)n * 58 + hh) * 7424);
    if (hh == 0 || hh == 57) {
      for (int o = t; o < 1856; o += 256) xpw[o] = 0;
      return;
    }
    int h = hh - 1;
    const int* xb = x + (size_t)n * C1 * HW + h * 56;
    for (int idx = t; idx < 7168; idx += 256) {
      int c = idx / 56, w = idx - c * 56;
      lds[w * 132 + c] = (signed char)__builtin_nontemporal_load(&xb[(size_t)c * HW + w]);
    }
    __syncthreads();
    for (int o = t; o < 1856; o += 256) {
      int kb = o / 232, r = o - kb * 232, ww = r >> 2, cw = r & 3;
      int val = (ww == 0 || ww == 57) ? 0
                : *(const int*)&lds[(ww - 1) * 132 + kb * 16 + cw * 4];
      xpw[o] = val;
    }
  } else if (b < 2432) {                 // 576 blocks: wDW
    int idx = (b - 1856) * 256 + t;      // exactly 147456
    int co = idx / 1152, r = idx - co * 1152;
    int ci = r / 9, pos = r - ci * 9;
    int k = pos * 128 + ci;
    wq1t[(size_t)(k >> 4) * 2048 + co * 16 + (k & 15)] = (signed char)(int)wDW[idx];
  } else if (b < 2560) {                 // 128 blocks: wPW
    int i = (b - 2432) * 256 + t;        // exactly 32768
    int co = i >> 7, ci = i & 127;
    wq2t[(size_t)(ci >> 4) * 4096 + co * 16 + (ci & 15)] = (signed char)(int)wPW[i];
  } else {
    if (t == 0) { st->absmax1 = 0; st->absmax2 = 0; }
    for (int c = t; c < C1; c += 256) {
      st->sum1[c] = 0; st->sumsq1[c] = 0; st->min1[c] = 127; st->max1[c] = -128;
    }
    for (int c = t; c < C2; c += 256) {
      st->sum2[c] = 0; st->sumsq2[c] = 0; st->min2[c] = 127; st->max2[c] = -128;
    }
  }
}

__device__ inline v4i ld16_lds(const signed char* p) {
  const int2* q = (const int2*)p;          // 8-byte aligned
  int2 lo = q[0], hi = q[1];
  v4i r; r[0] = lo.x; r[1] = lo.y; r[2] = hi.x; r[3] = hi.y;
  return r;
}

// 3x3 conv 128->128. 784 blocks x 128 pixels x 128 co; wave = 64 pix x 64 co.
// absmax1 + raw acc store (nontemporal, 256B coalesced).
__global__ __launch_bounds__(256, 4) void k_conv1s(
    const signed char* __restrict__ xp, const signed char* __restrict__ wq1t,
    int* __restrict__ acc1, Stats* st) {
  __shared__ int reda[4];
  int t = threadIdx.x, lane = t & 63, wave = t >> 6;
  int half = lane >> 5, l31 = lane & 31;
  int mw = wave & 1, nw = wave >> 1;
  size_t g0 = (size_t)blockIdx.x * 128;

  const signed char* ab[2];
#pragma unroll
  for (int i = 0; i < 2; ++i) {
    size_t gm = g0 + mw * 64 + i * 32 + l31;
    int n = (int)(gm / HW);
    int p = (int)(gm - (size_t)n * HW);
    int h = p / 56, w = p - h * 56;
    ab[i] = xp + ((size_t)n * 58 + h) * 7424 + w * 16 + half * 928;
  }
  const signed char* bb[2];
#pragma unroll
  for (int j = 0; j < 2; ++j)
    bb[j] = wq1t + (size_t)(nw * 64 + j * 32 + l31) * 16 + half * 2048;

  v16i a1[2][2];
#pragma unroll
  for (int i = 0; i < 2; ++i)
#pragma unroll
    for (int j = 0; j < 2; ++j)
#pragma unroll
      for (int r = 0; r < 16; ++r) a1[i][j][r] = 0;

#pragma unroll
  for (int pos = 0; pos < 9; ++pos) {
    int kh = pos / 3, kw = pos - kh * 3;
    const signed char* a0p = ab[0] + kh * 7424 + kw * 16;
    const signed char* a1p = ab[1] + kh * 7424 + kw * 16;
#pragma unroll
    for (int kb = 0; kb < 8; kb += 2) {
      v4i af0 = *(const v4i*)(a0p + kb * 928);
      v4i af1 = *(const v4i*)(a1p + kb * 928);
      v4i bf0 = *(const v4i*)(bb[0] + pos * 16384 + kb * 2048);
      v4i bf1 = *(const v4i*)(bb[1] + pos * 16384 + kb * 2048);
      a1[0][0] = __builtin_amdgcn_mfma_i32_32x32x32_i8(af0, bf0, a1[0][0], 0, 0, 0);
      a1[0][1] = __builtin_amdgcn_mfma_i32_32x32x32_i8(af0, bf1, a1[0][1], 0, 0, 0);
      a1[1][0] = __builtin_amdgcn_mfma_i32_32x32x32_i8(af1, bf0, a1[1][0], 0, 0, 0);
      a1[1][1] = __builtin_amdgcn_mfma_i32_32x32x32_i8(af1, bf1, a1[1][1], 0, 0, 0);
    }
  }

  int am = 0;
#pragma unroll
  for (int i = 0; i < 2; ++i)
#pragma unroll
    for (int j = 0; j < 2; ++j)
#pragma unroll
      for (int r = 0; r < 16; ++r) am = max(am, abs(a1[i][j][r]));
  for (int off = 32; off; off >>= 1) am = max(am, __shfl_down(am, off, 64));
  if (lane == 0) reda[wave] = am;
  __syncthreads();
  if (t == 0)
    atomicMax(&st->absmax1, max(max(reda[0], reda[1]), max(reda[2], reda[3])));

  int* ob = acc1 + (size_t)blockIdx.x * 16384;
#pragma unroll
  for (int i = 0; i < 2; ++i)
#pragma unroll
    for (int j = 0; j < 2; ++j)
#pragma unroll
      for (int reg = 0; reg < 16; ++reg)
        __builtin_nontemporal_store(
            a1[i][j][reg], &ob[(((wave * 2 + i) * 2 + j) * 16 + reg) * 64 + lane]);
}

// read acc1 raw (nontemporal, coalesced), quantize -> q1 [g][128] + stats.
// scale1 inline from absmax1 (exact integer math). 784 blocks x 128 pix.
__global__ __launch_bounds__(256, 4) void k_qstats1(
    const int* __restrict__ acc1, signed char* __restrict__ q1, Stats* st,
    const float* __restrict__ x_exp, const float* __restrict__ wDW_exp) {
  __shared__ int qti[128 * 34];
  __shared__ int psum[C1], psq[C1], pmn[C1], pmx[C1];
  signed char* qt = (signed char*)qti;
  int t = threadIdx.x, lane = t & 63, wave = t >> 6;
  int half = lane >> 5, l31 = lane & 31;
  int mw = wave & 1, nw = wave >> 1;

  if (t < C1) { psum[t] = 0; psq[t] = 0; pmn[t] = 127; pmx[t] = -128; }
  __syncthreads();

  int v1 = st->absmax1;
  int pw = 31 - __clz(v1 | 1);
  int bw = ((v1 & (v1 - 1)) == 0) ? pw : pw + 1;
  int sh = max(bw - 7, 0);
  float scale1 = exp2f((float)(-sh));
  if (blockIdx.x == 0 && t == 0)
    st->e1 = x_exp[0] + wDW_exp[0] + (float)sh;

  const int* ib = acc1 + (size_t)blockIdx.x * 16384;
#pragma unroll
  for (int j = 0; j < 2; ++j) {
    int sj = 0, sqj = 0, mnj = 127, mxj = -128;
    int c = nw * 64 + j * 32 + l31;
#pragma unroll
    for (int i = 0; i < 2; ++i)
#pragma unroll
      for (int reg = 0; reg < 16; ++reg) {
        int av = __builtin_nontemporal_load(
            &ib[(((wave * 2 + i) * 2 + j) * 16 + reg) * 64 + lane]);
        int row = (reg & 3) + 8 * (reg >> 2) + 4 * half;
        int pix = mw * 64 + i * 32 + row;
        float r = rintf((float)av * scale1);
        r = fminf(fmaxf(r, -128.f), 127.f);
        int qi = (int)r;
        qt[pix * 136 + c] = (signed char)qi;
        sj += qi; sqj += qi * qi; mnj = min(mnj, qi); mxj = max(mxj, qi);
      }
    sj += __shfl_down(sj, 32, 64);
    sqj += __shfl_down(sqj, 32, 64);
    mnj = min(mnj, __shfl_down(mnj, 32, 64));
    mxj = max(mxj, __shfl_down(mxj, 32, 64));
    if (half == 0) {
      atomicAdd(&psum[c], sj); atomicAdd(&psq[c], sqj);
      atomicMin(&pmn[c], mnj); atomicMax(&pmx[c], mxj);
    }
  }
  __syncthreads();
  if (t < C1) {
    atomicAdd(&st->sum1[t], psum[t]);
    atomicAdd(&st->sumsq1[t], (unsigned)psq[t]);
    atomicMin(&st->min1[t], pmn[t]);
    atomicMax(&st->max1[t], pmx[t]);
  }
  int* q1w = (int*)(q1 + (size_t)blockIdx.x * 128 * 128);
  for (int idx = t; idx < 4096; idx += 256) {
    int pix = idx >> 5, c4 = idx & 31;
    q1w[idx] = qti[pix * 34 + c4];
  }
}

// 1x1 conv 128->256. Block = 128 pix x 256 co; wave = 32 pix.
// bn1 in-block from global stats (bit-identical). LDS union: stg overlays qti.
// (256,2): ~116 live VGPRs — (256,4) caused scratch spills (r9).
template <int STORE>
__global__ __launch_bounds__(256, 2) void k_conv2t(
    const signed char* __restrict__ q1, const signed char* __restrict__ wq2t,
    signed char* __restrict__ q3, Stats* st,
    const float* __restrict__ gamma1, const float* __restrict__ beta1,
    const float* __restrict__ wPW_exp) {
  __shared__ int bufi[8448];               // 33792 B: qti [128][34] / stg [128][264]
  __shared__ int psum[C2], psq[C2], pmn[C2], pmx[C2];
  __shared__ float bnA[C1], bnB[C1], redf[2];
  __shared__ int reda[4];
  signed char* qt = (signed char*)bufi;
  signed char* stg = (signed char*)bufi;

  int t = threadIdx.x, lane = t & 63, wave = t >> 6;
  int half = lane >> 5, l31 = lane & 31;
  size_t g0 = (size_t)blockIdx.x * 128;

  if (STORE) { psum[t] = 0; psq[t] = 0; pmn[t] = 127; pmx[t] = -128; }

  // ---- bn1 (redundant per block; ops identical to reference chain) ----
  float e1 = st->e1;
  float cand = 0.f;
  if (t < C1) {
    double meanq = (double)st->sum1[t] / (double)NHW;
    double varq = (double)st->sumsq1[t] / (double)NHW - meanq * meanq;
    float se = exp2f(e1);
    float mean = (float)meanq * se;
    float var = (float)varq * se * se;
    float rsq = 1.0f / sqrtf(var + 1e-5f);
    float g = gamma1[t], b = beta1[t];
    float Avv = g * se * rsq;
    float Bvv = b - g * mean * rsq;
    bnA[t] = Avv; bnB[t] = Bvv;
    cand = fmaxf(fabsf(Avv * (float)st->min1[t] + Bvv),
                 fabsf(Avv * (float)st->max1[t] + Bvv));
  }
  if (wave < 2) {
    for (int off = 32; off; off >>= 1) cand = fmaxf(cand, __shfl_down(cand, off, 64));
    if (lane == 0) redf[wave] = cand;
  }
  __syncthreads();
  float rng = fmaxf(redf[0], redf[1]);
  float bwv = ceilf(log2f(rng));
  float s2 = exp2f(7.0f - bwv);
  float e2 = bwv - 7.0f;

  // ---- rebuild q2 tile in LDS ----
  int c4 = t & 31;
  float Av[4], Bv[4];
#pragma unroll
  for (int jj = 0; jj < 4; ++jj) {
    Av[jj] = bnA[c4 * 4 + jj];
    Bv[jj] = bnB[c4 * 4 + jj];
  }
  const int* q1w = (const int*)(q1 + g0 * 128);
#pragma unroll
  for (int k = 0; k < 16; ++k) {
    int idx = k * 256 + t;
    int v = q1w[idx];
    int pix = idx >> 5;
    int outv = 0;
#pragma unroll
    for (int jj = 0; jj < 4; ++jj) {
      int b = (signed char)(v >> (8 * jj));
      float y = Av[jj] * (float)b + Bv[jj];
      float r = rintf(y * s2);
      r = fminf(fmaxf(r, -128.f), 127.f);
      r = fmaxf(r, 0.f);
      outv |= ((int)r & 0xff) << (8 * jj);
    }
    bufi[pix * 34 + c4] = outv;
  }
  __syncthreads();

  // ---- MFMA (ch-loop, acc[4] reused) ----
  int am2 = 0;
  float scale2 = 0.f;
  int sh2 = 0;
  if (STORE) {
    int v2 = st->absmax2;
    int pw = 31 - __clz(v2 | 1);
    int bw = ((v2 & (v2 - 1)) == 0) ? pw : pw + 1;
    sh2 = max(bw - 7, 0);
    scale2 = exp2f((float)(-sh2));
    if (blockIdx.x == 0 && t == 0)
      st->e3 = e2 + wPW_exp[0] + (float)sh2;
  }
  int pq[2][4][4];
#pragma unroll
  for (int ch = 0; ch < 2; ++ch) {
    v16i acc[4];
#pragma unroll
    for (int j = 0; j < 4; ++j)
#pragma unroll
      for (int r = 0; r < 16; ++r) acc[j][r] = 0;
#pragma unroll
    for (int ks = 0; ks < 4; ++ks) {
      v4i af = ld16_lds(&qt[(wave * 32 + l31) * 136 + half * 16 + ks * 32]);
#pragma unroll
      for (int j = 0; j < 4; ++j) {
        v4i bf = *(const v4i*)(wq2t + (size_t)(ks * 2 + half) * 4096 +
                               (ch * 128 + j * 32 + l31) * 16);
        acc[j] = __builtin_amdgcn_mfma_i32_32x32x32_i8(af, bf, acc[j], 0, 0, 0);
      }
    }
    if (STORE == 0) {
#pragma unroll
      for (int j = 0; j < 4; ++j)
#pragma unroll
        for (int r = 0; r < 16; ++r) am2 = max(am2, abs(acc[j][r]));
    } else {
#pragma unroll
      for (int j = 0; j < 4; ++j) {
        int c = ch * 128 + j * 32 + l31;
        int sj = 0, sqj = 0, mnj = 127, mxj = -128;
        int pk[4] = {0, 0, 0, 0};
#pragma unroll
        for (int reg = 0; reg < 16; ++reg) {
          float r = rintf((float)acc[j][reg] * scale2);
          r = fminf(fmaxf(r, -128.f), 127.f);
          int qi = (int)r;
          pk[reg >> 2] |= (qi & 0xff) << ((reg & 3) * 8);
          sj += qi; sqj += qi * qi; mnj = min(mnj, qi); mxj = max(mxj, qi);
        }
#pragma unroll
        for (int k = 0; k < 4; ++k) pq[ch][j][k] = pk[k];
        sj += __shfl_down(sj, 32, 64);
        sqj += __shfl_down(sqj, 32, 64);
        mnj = min(mnj, __shfl_down(mnj, 32, 64));
        mxj = max(mxj, __shfl_down(mxj, 32, 64));
        if (half == 0) {
          atomicAdd(&psum[c], sj); atomicAdd(&psq[c], sqj);
          atomicMin(&pmn[c], mnj); atomicMax(&pmx[c], mxj);
        }
      }
    }
  }

  if (STORE == 0) {
    for (int off = 32; off; off >>= 1) am2 = max(am2, __shfl_down(am2, off, 64));
    if (lane == 0) reda[wave] = am2;
    __syncthreads();
    if (t == 0)
      atomicMax(&st->absmax2, max(max(reda[0], reda[1]), max(reda[2], reda[3])));
  } else {
    __syncthreads();   // all qt reads done; safe to overlay stg
#pragma unroll
    for (int ch = 0; ch < 2; ++ch)
#pragma unroll
      for (int j = 0; j < 4; ++j)
#pragma unroll
        for (int k = 0; k < 4; ++k) {
          int word = pq[ch][j][k];
#pragma unroll
          for (int b = 0; b < 4; ++b) {
            int row = b + 8 * k + 4 * half;
            stg[(wave * 32 + row) * 264 + ch * 128 + j * 32 + l31] =
                (signed char)(word >> (8 * b));
          }
        }
    __syncthreads();
    atomicAdd(&st->sum2[t], psum[t]);
    atomicAdd(&st->sumsq2[t], (unsigned)psq[t]);
    atomicMin(&st->min2[t], pmn[t]);
    atomicMax(&st->max2[t], pmx[t]);
    int* q3w = (int*)(q3 + g0 * 256);
#pragma unroll
    for (int k = 0; k < 32; ++k) {
      int idx = k * 256 + t;
      int pix = idx >> 6, cw = idx & 63;
      q3w[idx] = *(const int*)&stg[pix * 264 + cw * 4];
    }
  }
}

// final: bn2 in-block (bit-identical), q3 -> out NCHW float via LDS transpose.
// q3 reads + out stores nontemporal (single-use streams).
__global__ __launch_bounds__(256) void k_out(
    const signed char* __restrict__ q3, const Stats* __restrict__ st,
    const float* __restrict__ gamma2, const float* __restrict__ beta2,
    float* __restrict__ out) {
  __shared__ signed char lds[64 * 260];
  __shared__ float bnA2[C2], bnB2[C2], redf2[4];
  int t = threadIdx.x, lane = t & 63, wave = t >> 6;
  size_t g0 = (size_t)blockIdx.x * 64;     // 1568 blocks
  int n = (int)(g0 / HW), p0 = (int)(g0 - (size_t)n * HW);
  const int* q3w = (const int*)(q3 + g0 * 256);
#pragma unroll
  for (int k = 0; k < 16; ++k) {
    int idx = k * 256 + t;
    int pix = idx >> 6, cw = idx & 63;
    *(int*)&lds[pix * 260 + cw * 4] = __builtin_nontemporal_load(&q3w[idx]);
  }
  // bn2 (redundant per block; ops identical to reference chain)
  float e3 = st->e3;
  {
    double meanq = (double)st->sum2[t] / (double)NHW;
    double varq = (double)st->sumsq2[t] / (double)NHW - meanq * meanq;
    float se = exp2f(e3);
    float mean = (float)meanq * se;
    float var = (float)varq * se * se;
    float rsq = 1.0f / sqrtf(var + 1e-5f);
    float g = gamma2[t], b = beta2[t];
    float Avv = g * se * rsq;
    float Bvv = b - g * mean * rsq;
    bnA2[t] = Avv; bnB2[t] = Bvv;
    float cand = fmaxf(fabsf(Avv * (float)st->min2[t] + Bvv),
                       fabsf(Avv * (float)st->max2[t] + Bvv));
    for (int off = 32; off; off >>= 1) cand = fmaxf(cand, __shfl_down(cand, off, 64));
    if (lane == 0) redf2[wave] = cand;
  }
  __syncthreads();
  float rng = fmaxf(fmaxf(redf2[0], redf2[1]), fmaxf(redf2[2], redf2[3]));
  float bwv = ceilf(log2f(rng));
  float sf = exp2f(7.0f - bwv);
  if (blockIdx.x == 0 && t == 0) out[N2] = bwv - 7.0f;

  float* ob = out + (size_t)n * C2 * HW + p0 + lane;
#pragma unroll
  for (int cg = 0; cg < 16; ++cg) {
    int v = *(const int*)&lds[lane * 260 + wave * 64 + cg * 4];
#pragma unroll
    for (int jj = 0; jj < 4; ++jj) {
      int c = wave * 64 + cg * 4 + jj;
      float y = bnA2[c] * (float)((signed char)(v >> (8 * jj))) + bnB2[c];
      float r = rintf(y * sf);
      r = fminf(fmaxf(r, -128.f), 127.f);
      __builtin_nontemporal_store(fmaxf(r, 0.f), &ob[(size_t)c * HW]);
    }
  }
}

extern "C" void kernel_launch(void* const* d_in, const int* in_sizes, int n_in,
                              void* d_out, int out_size, void* d_ws, size_t ws_size,
                              hipStream_t stream) {
  const int* x = (const int*)d_in[0];
  const float* x_exp = (const float*)d_in[1];
  const float* wDW = (const float*)d_in[2];
  const float* wDW_exp = (const float*)d_in[3];
  const float* wPW = (const float*)d_in[4];
  const float* wPW_exp = (const float*)d_in[5];
  const float* gamma1 = (const float*)d_in[6];
  const float* beta1 = (const float*)d_in[7];
  const float* gamma2 = (const float*)d_in[8];
  const float* beta2 = (const float*)d_in[9];
  float* out = (float*)d_out;

  char* ws = (char*)d_ws;
  signed char* xp2 = (signed char*)(ws + OFF_XP);
  int* acc1 = (int*)(ws + OFF_ACC1);
  signed char* q1 = (signed char*)(ws + OFF_Q1);
  signed char* q3 = (signed char*)(ws + OFF_Q3);
  signed char* wq1t = (signed char*)(ws + OFF_WQ1);
  signed char* wq2t = (signed char*)(ws + OFF_WQ2);
  Stats* st = (Stats*)(ws + OFF_STATS);

  hipLaunchKernelGGL(k_prep, dim3(2561), dim3(256), 0, stream,
                     x, wDW, wPW, xp2, wq1t, wq2t, st);

  hipLaunchKernelGGL(k_conv1s, dim3(784), dim3(256), 0, stream,
                     xp2, wq1t, acc1, st);
  hipLaunchKernelGGL(k_qstats1, dim3(784), dim3(256), 0, stream,
                     acc1, q1, st, x_exp, wDW_exp);

  hipLaunchKernelGGL(k_conv2t<0>, dim3(784), dim3(256), 0, stream,
                     q1, wq2t, q3, st, gamma1, beta1, wPW_exp);
  hipLaunchKernelGGL(k_conv2t<1>, dim3(784), dim3(256), 0, stream,
                     q1, wq2t, q3, st, gamma1, beta1, wPW_exp);

  hipLaunchKernelGGL(k_out, dim3(1568), dim3(256), 0, stream,
                     q3, st, gamma2, beta2, out);
}